// Round 6
// baseline (863.364 us; speedup 1.0000x reference)
//
#include <hip/hip_runtime.h>
#include <hip/hip_bf16.h>
#include <math.h>

#define SEQn 2048
#define HID  2048
#define NH   16
#define HD   128

typedef __attribute__((ext_vector_type(8))) __bf16 bf16x8;
typedef __attribute__((ext_vector_type(4))) float  f32x4;

#define MFMA16(a,b,c) __builtin_amdgcn_mfma_f32_16x16x32_bf16((a),(b),(c),0,0,0)

__device__ __forceinline__ ushort f2bf(float f) {
  union { float f; unsigned u; } v; v.f = f;
  unsigned r = v.u + 0x7fffu + ((v.u >> 16) & 1u);
  return (ushort)(r >> 16);
}
__device__ __forceinline__ float bf2f(ushort u) {
  union { unsigned u; float f; } v; v.u = ((unsigned)u) << 16; return v.f;
}
__device__ __forceinline__ void split2(float x, ushort& h, ushort& l) {
  h = f2bf(x);
  l = f2bf(x - bf2f(h));   // x-hi exact; total err <= ~2^-17 |x|
}
__device__ __forceinline__ void gl_lds16(const ushort* g, ushort* l) {
  __builtin_amdgcn_global_load_lds((const __attribute__((address_space(1))) unsigned int*)g,
                                   (__attribute__((address_space(3))) unsigned int*)l, 16, 0, 0);
}

// ---------------- RoPE tables: cos/sin [SEQ][64] ----------------
__global__ void k_rope_tables(const int* __restrict__ pos,
                              float* __restrict__ cosT, float* __restrict__ sinT) {
  int t = threadIdx.x;
  int s = blockIdx.x * 4 + (t >> 6), i = t & 63;
  float p = (float)pos[s];
  float ex = (float)(2 * i) / 128.0f;
  float invf = 1.0f / powf(10000.0f, ex);
  float f = p * invf;
  cosT[s * 64 + i] = cosf(f);
  sinT[s * 64 + i] = sinf(f);
}

// ---------------- split f32 -> bf16 hi/lo (x4 vectorized) ----------------
__global__ void k_split(const float* __restrict__ x,
                        ushort* __restrict__ hi, ushort* __restrict__ lo, int n4) {
  int i = blockIdx.x * blockDim.x + threadIdx.x;
  if (i >= n4) return;
  const float4 v = ((const float4*)x)[i];
  ushort4 h, l;
  split2(v.x, h.x, l.x); split2(v.y, h.y, l.y);
  split2(v.z, h.z, l.z); split2(v.w, h.w, l.w);
  ((ushort4*)hi)[i] = h; ((ushort4*)lo)[i] = l;
}

// ------- transpose + split 3 weights in one dispatch: W[z][K][N] f32 -> WT[z][N][K] bf16 hi/lo ----
__global__ void k_splitT3(const float* __restrict__ W0, const float* __restrict__ W1,
                          const float* __restrict__ W2,
                          ushort* __restrict__ Th, ushort* __restrict__ Tl) {
  __shared__ float tile[32][33];
  const float* W = (blockIdx.z == 0) ? W0 : (blockIdx.z == 1) ? W1 : W2;
  ushort* Thz = Th + (size_t)blockIdx.z * HID * HID;
  ushort* Tlz = Tl + (size_t)blockIdx.z * HID * HID;
  int kb = blockIdx.x * 32, nb = blockIdx.y * 32;
  int tx = threadIdx.x, ty = threadIdx.y;   // 32 x 8
#pragma unroll
  for (int r = 0; r < 4; r++)
    tile[ty + r * 8][tx] = W[(size_t)(kb + ty + r * 8) * HID + nb + tx];
  __syncthreads();
#pragma unroll
  for (int r = 0; r < 4; r++) {
    int n = nb + ty + r * 8, k = kb + tx;
    ushort h, l; split2(tile[tx][ty + r * 8], h, l);
    Thz[(size_t)n * HID + k] = h;
    Tlz[(size_t)n * HID + k] = l;
  }
}

// ---------------- GEMM: C[z][M][N] = A * B[z]^T-stored, bf16x3 (Ah*Bh + Ah*Bl + Al*Bh) ----
// A hi/lo: [2048][2048] bf16 row-major (K contiguous). B hi/lo: z planes of [N][K] bf16.
__global__ __launch_bounds__(512) void k_gemm_x3(
    const ushort* __restrict__ Ah, const ushort* __restrict__ Al,
    const ushort* __restrict__ Bh, const ushort* __restrict__ Bl,
    float* __restrict__ C) {
  __shared__ alignas(16) ushort lds[4][128 * 32];
  const int t = threadIdx.x, lane = t & 63, w = t >> 6;  // 8 waves
  const int bm = blockIdx.y * 128, bn = blockIdx.x * 128;
  const size_t zb = (size_t)blockIdx.z * HID * HID;
  const int lr = lane & 15, lg = lane >> 4;
  const int sr = t >> 2, sc = (t & 3) * 8;
  const ushort* ga  = Ah + (size_t)(bm + sr) * HID + sc;
  const ushort* gal = Al + (size_t)(bm + sr) * HID + sc;
  const ushort* gb  = Bh + zb + (size_t)(bn + sr) * HID + sc;
  const ushort* gbl = Bl + zb + (size_t)(bn + sr) * HID + sc;
  ushort* l0 = &lds[0][w * 512];   // wave-uniform base; lane*16B == row-major (sr,sc)
  ushort* l1 = &lds[1][w * 512];
  ushort* l2 = &lds[2][w * 512];
  ushort* l3 = &lds[3][w * 512];
  const int wr = (w & 3) * 32, wc = (w >> 2) * 64;   // wave tile: 32 rows x 64 cols
  f32x4 acc[2][4] = {};
  for (int k0 = 0; k0 < HID; k0 += 32) {
    __syncthreads();                      // WAR: all waves done reading previous tile
    gl_lds16(ga  + k0, l0);
    gl_lds16(gal + k0, l1);
    gl_lds16(gb  + k0, l2);
    gl_lds16(gbl + k0, l3);
    __syncthreads();                      // compiler drains vmcnt before s_barrier
    bf16x8 a_h[2], a_l[2], b_h[4], b_l[4];
#pragma unroll
    for (int mi = 0; mi < 2; mi++) {
      int ro = (wr + mi * 16 + lr) * 32 + lg * 8;
      a_h[mi] = *(const bf16x8*)&lds[0][ro];
      a_l[mi] = *(const bf16x8*)&lds[1][ro];
    }
#pragma unroll
    for (int ni = 0; ni < 4; ni++) {
      int ro = (wc + ni * 16 + lr) * 32 + lg * 8;
      b_h[ni] = *(const bf16x8*)&lds[2][ro];
      b_l[ni] = *(const bf16x8*)&lds[3][ro];
    }
#pragma unroll
    for (int mi = 0; mi < 2; mi++)
#pragma unroll
      for (int ni = 0; ni < 4; ni++) {
        acc[mi][ni] = MFMA16(a_h[mi], b_h[ni], acc[mi][ni]);
        acc[mi][ni] = MFMA16(a_h[mi], b_l[ni], acc[mi][ni]);
        acc[mi][ni] = MFMA16(a_l[mi], b_h[ni], acc[mi][ni]);
      }
  }
  float* Cz = C + (size_t)blockIdx.z * SEQn * HID;
#pragma unroll
  for (int mi = 0; mi < 2; mi++)
#pragma unroll
    for (int ni = 0; ni < 4; ni++)
#pragma unroll
      for (int j = 0; j < 4; j++) {
        int row = bm + wr + mi * 16 + lg * 4 + j;   // C/D: row=(lane>>4)*4+j
        int col = bn + wc + ni * 16 + lr;           //      col=lane&15
        Cz[(size_t)row * HID + col] = acc[mi][ni][j];
      }
}

// ---------------- RoPE apply + convert Q,K: [s][h*128+d] f32 -> [h][s][d] bf16 hi/lo ----------------
// Q is pre-scaled by 1/sqrt(HD) here so the attention kernel's scores need no extra multiply.
__global__ void k_rope_qk(const float* __restrict__ Qf, const float* __restrict__ Kf,
                          const float* __restrict__ cosT, const float* __restrict__ sinT,
                          ushort* __restrict__ Qhh, ushort* __restrict__ Qll,
                          ushort* __restrict__ Khh, ushort* __restrict__ Kll) {
  int t = threadIdx.x;
  int s = blockIdx.x * 4 + (t >> 6), h = blockIdx.y, d = t & 63;
  const float scale = 0.08838834764831845f;  // 1/sqrt(128)
  float c = cosT[s * 64 + d], sn = sinT[s * 64 + d];
  size_t in0  = (size_t)s * HID + h * HD + d;
  size_t out0 = ((size_t)h * SEQn + s) * HD + d;
  ushort hh, ll;
  {
    float q1 = Qf[in0] * scale, q2 = Qf[in0 + 64] * scale;
    split2(q1 * c - q2 * sn, hh, ll); Qhh[out0] = hh;      Qll[out0] = ll;
    split2(q2 * c + q1 * sn, hh, ll); Qhh[out0 + 64] = hh; Qll[out0 + 64] = ll;
  }
  {
    float k1 = Kf[in0], k2 = Kf[in0 + 64];
    split2(k1 * c - k2 * sn, hh, ll); Khh[out0] = hh;      Kll[out0] = ll;
    split2(k2 * c + k1 * sn, hh, ll); Khh[out0 + 64] = hh; Kll[out0 + 64] = ll;
  }
}

// ---------------- V: [s][h*128+d] f32 -> V^T [h][d][s] bf16 hi/lo ----------------
__global__ void k_transpose_v(const float* __restrict__ Vf,
                              ushort* __restrict__ Vth, ushort* __restrict__ Vtl) {
  __shared__ float tile[32][33];
  int h = blockIdx.x, db = blockIdx.y * 32, sb = blockIdx.z * 32;
  int tx = threadIdx.x, ty = threadIdx.y;  // 32 x 8
#pragma unroll
  for (int r = 0; r < 4; r++)
    tile[ty + r * 8][tx] = Vf[(size_t)(sb + ty + r * 8) * HID + h * HD + db + tx];
  __syncthreads();
#pragma unroll
  for (int r = 0; r < 4; r++) {
    int d = db + ty + r * 8, s = sb + tx;
    ushort hh, ll; split2(tile[tx][ty + r * 8], hh, ll);
    size_t o = ((size_t)h * HD + d) * SEQn + s;
    Vth[o] = hh; Vtl[o] = ll;
  }
}

// ---------------- Flash attention, causal. 4 waves x 16 q-rows = 64 q-rows per block ------------
// Heavy blocks (large qb) launched first via index reversal. Waves are barrier-free in the
// KV loop (private P tiles) -> phase-skewed, so setprio around MFMA clusters applies (T5/m191).
// Q arrives pre-scaled by 1/sqrt(HD). Writes O as bf16 hi/lo planes in [s][h*128+d] layout.
__global__ __launch_bounds__(256) void k_attn(
    const ushort* __restrict__ Qhh, const ushort* __restrict__ Qll,
    const ushort* __restrict__ Khh, const ushort* __restrict__ Kll,
    const ushort* __restrict__ Vth, const ushort* __restrict__ Vtl,
    ushort* __restrict__ Ohi, ushort* __restrict__ Olo) {
  __shared__ alignas(16) ushort plds[4][2][16 * 72];   // per-wave P hi/lo tiles, stride 72 (144B = 9x16B)
  const int t = threadIdx.x, lane = t & 63, w = t >> 6;
  const int h = blockIdx.y;
  const int qb = (gridDim.x - 1 - blockIdx.x) * 64;   // heaviest first
  const int lr = lane & 15, lg = lane >> 4;
  const int q0 = qb + w * 16;
  const size_t qoff = ((size_t)h * SEQn + q0 + lr) * HD + lg * 8;
  bf16x8 qh[4], ql[4];
#pragma unroll
  for (int ks = 0; ks < 4; ks++) {
    qh[ks] = *(const bf16x8*)(Qhh + qoff + ks * 32);
    ql[ks] = *(const bf16x8*)(Qll + qoff + ks * 32);
  }
  f32x4 o[8] = {};
  float mrow[4], lrow[4];
#pragma unroll
  for (int j = 0; j < 4; j++) { mrow[j] = -INFINITY; lrow[j] = 0.f; }
  ushort* myph = &plds[w][0][0];
  ushort* mypl = &plds[w][1][0];

  for (int kv0 = 0; kv0 <= qb; kv0 += 64) {
    // ---- scores: S = (Q @ K^T) (pre-scaled), 16 x 64 per wave, bf16x3 ----
    f32x4 s4[4] = {};
    __builtin_amdgcn_s_setprio(1);
#pragma unroll
    for (int ni = 0; ni < 4; ni++) {
      const size_t koff = ((size_t)h * SEQn + kv0 + ni * 16 + lr) * HD + lg * 8;
#pragma unroll
      for (int ks = 0; ks < 4; ks++) {
        bf16x8 kh = *(const bf16x8*)(Khh + koff + ks * 32);
        bf16x8 kl = *(const bf16x8*)(Kll + koff + ks * 32);
        s4[ni] = MFMA16(qh[ks], kh, s4[ni]);
        s4[ni] = MFMA16(qh[ks], kl, s4[ni]);
        s4[ni] = MFMA16(ql[ks], kh, s4[ni]);
      }
    }
    __builtin_amdgcn_s_setprio(0);
    // ---- online softmax (per q-row; rows live in fixed 16-lane groups) ----
    float sf[4];
#pragma unroll
    for (int j = 0; j < 4; j++) {
      const int row = q0 + lg * 4 + j;
      float sc[4];
#pragma unroll
      for (int ni = 0; ni < 4; ni++) {
        int col = kv0 + ni * 16 + lr;
        sc[ni] = (col <= row) ? s4[ni][j] : -INFINITY;
      }
      float rm = fmaxf(fmaxf(sc[0], sc[1]), fmaxf(sc[2], sc[3]));
#pragma unroll
      for (int off = 1; off < 16; off <<= 1) rm = fmaxf(rm, __shfl_xor(rm, off));
      float mn = fmaxf(mrow[j], rm);
      sf[j] = __expf(mrow[j] - mn);
      float rs = 0.f;
#pragma unroll
      for (int ni = 0; ni < 4; ni++) {
        float pv = __expf(sc[ni] - mn);
        rs += pv;
        ushort hh, ll; split2(pv, hh, ll);
        myph[(lg * 4 + j) * 72 + ni * 16 + lr] = hh;
        mypl[(lg * 4 + j) * 72 + ni * 16 + lr] = ll;
      }
#pragma unroll
      for (int off = 1; off < 16; off <<= 1) rs += __shfl_xor(rs, off);
      lrow[j] = lrow[j] * sf[j] + rs;
      mrow[j] = mn;
    }
#pragma unroll
    for (int nn = 0; nn < 8; nn++) {
      o[nn][0] *= sf[0]; o[nn][1] *= sf[1]; o[nn][2] *= sf[2]; o[nn][3] *= sf[3];
    }
    // ---- P via LDS (C-layout -> A-frag layout), then PV with hi/lo P and V ----
    bf16x8 p0h = *(const bf16x8*)&myph[lr * 72 + lg * 8];
    bf16x8 p1h = *(const bf16x8*)&myph[lr * 72 + lg * 8 + 32];
    bf16x8 p0l = *(const bf16x8*)&mypl[lr * 72 + lg * 8];
    bf16x8 p1l = *(const bf16x8*)&mypl[lr * 72 + lg * 8 + 32];
    __builtin_amdgcn_s_setprio(1);
#pragma unroll
    for (int nn = 0; nn < 8; nn++) {
      const size_t voff = ((size_t)h * HD + nn * 16 + lr) * SEQn + kv0 + lg * 8;
      bf16x8 vh0 = *(const bf16x8*)(Vth + voff);
      bf16x8 vl0 = *(const bf16x8*)(Vtl + voff);
      bf16x8 vh1 = *(const bf16x8*)(Vth + voff + 32);
      bf16x8 vl1 = *(const bf16x8*)(Vtl + voff + 32);
      o[nn] = MFMA16(p0h, vh0, o[nn]);
      o[nn] = MFMA16(p0h, vl0, o[nn]);
      o[nn] = MFMA16(p0l, vh0, o[nn]);
      o[nn] = MFMA16(p1h, vh1, o[nn]);
      o[nn] = MFMA16(p1h, vl1, o[nn]);
      o[nn] = MFMA16(p1l, vh1, o[nn]);
    }
    __builtin_amdgcn_s_setprio(0);
  }
  // ---- epilogue: normalize + hi/lo split, write [s][h*128+d] ----
#pragma unroll
  for (int nn = 0; nn < 8; nn++)
#pragma unroll
    for (int j = 0; j < 4; j++) {
      int row = q0 + lg * 4 + j;
      int col = h * HD + nn * 16 + lr;
      ushort hh, ll; split2(o[nn][j] / lrow[j], hh, ll);
      Ohi[(size_t)row * HID + col] = hh;
      Olo[(size_t)row * HID + col] = ll;
    }
}

extern "C" void kernel_launch(void* const* d_in, const int* in_sizes, int n_in,
                              void* d_out, int out_size, void* d_ws, size_t ws_size,
                              hipStream_t stream) {
  const float* Hf  = (const float*)d_in[0];
  // d_in[1] = attention_mask (pure causal by construction; applied analytically)
  const int*   pos = (const int*)d_in[2];
  const float* Wq  = (const float*)d_in[3];
  const float* Wk  = (const float*)d_in[4];
  const float* Wv  = (const float*)d_in[5];
  const float* Wo  = (const float*)d_in[6];

  char* ws = (char*)d_ws;
  const size_t SZ_TBL = (size_t)SEQn * 64 * 4;      // 512 KB
  const size_t SZ_BF  = (size_t)SEQn * HID * 2;     // 8 MB  (bf16 plane)
  const size_t SZ_F   = (size_t)SEQn * HID * 4;     // 16 MB (f32 plane)
  const size_t PLANE  = (size_t)HID * HID;          // ushorts per bf16 plane
  size_t off = 0;
  float*  cosT = (float*)(ws + off);  off += SZ_TBL;
  float*  sinT = (float*)(ws + off);  off += SZ_TBL;
  ushort* Hhi  = (ushort*)(ws + off); off += SZ_BF;
  ushort* Hlo  = (ushort*)(ws + off); off += SZ_BF;
  ushort* W3h  = (ushort*)(ws + off); off += 3 * SZ_BF;  // 3 transposed weight planes (hi)
  ushort* W3l  = (ushort*)(ws + off); off += 3 * SZ_BF;  // 3 transposed weight planes (lo)
  float*  QKVf = (float*)(ws + off);  off += 3 * SZ_F;   // Q,K,V f32 contiguous
  // total ws: ~113 MB
  float*  Qf = QKVf;
  float*  Kf = QKVf + (size_t)SEQn * HID;
  float*  Vf = QKVf + 2 * (size_t)SEQn * HID;
  // Overlays (serialized by stream order):
  //  - W3 planes are dead as weights after the fused QKV GEMM; rope/transpose
  //    write the bf16 Q/K/V planes there.
  //  - After attention, Qhh(W3h p0) and Kll(W3l p0) are dead; splitT(Wo) reuses them.
  //  - f32 K plane is dead after rope_qk; attention writes O hi/lo there.
  ushort* Qhh = W3h;
  ushort* Qll = W3h + PLANE;
  ushort* Khh = W3h + 2 * PLANE;
  ushort* Kll = W3l;
  ushort* Vth = W3l + PLANE;
  ushort* Vtl = W3l + 2 * PLANE;
  ushort* Ohi = (ushort*)Kf;
  ushort* Olo = (ushort*)((char*)Kf + SZ_BF);

  const int n4 = SEQn * HID / 4;

  k_rope_tables<<<dim3(SEQn / 4), dim3(256), 0, stream>>>(pos, cosT, sinT);
  k_split<<<dim3(n4 / 256), dim3(256), 0, stream>>>(Hf, Hhi, Hlo, n4);

  // all three QKV weights in one dispatch
  k_splitT3<<<dim3(64, 64, 3), dim3(32, 8), 0, stream>>>(Wq, Wk, Wv, W3h, W3l);

  // fused QKV projection: 768 blocks (~3 blocks/CU) vs 3x256
  k_gemm_x3<<<dim3(16, 16, 3), dim3(512), 0, stream>>>(Hhi, Hlo, W3h, W3l, QKVf);

  k_rope_qk<<<dim3(SEQn / 4, NH), dim3(256), 0, stream>>>(Qf, Kf, cosT, sinT, Qhh, Qll, Khh, Kll);
  k_transpose_v<<<dim3(NH, 4, 64), dim3(32, 8), 0, stream>>>(Vf, Vth, Vtl);

  k_attn<<<dim3(SEQn / 64, NH), dim3(256), 0, stream>>>(Qhh, Qll, Khh, Kll, Vth, Vtl, Ohi, Olo);

  // output projection (weight plane 0 reused for Wo; Qhh/Kll dead by now)
  k_splitT3<<<dim3(64, 64, 1), dim3(32, 8), 0, stream>>>(Wo, Wo, Wo, W3h, W3l);
  k_gemm_x3<<<dim3(16, 16, 1), dim3(512), 0, stream>>>(Ohi, Olo, W3h, W3l, (float*)d_out);
}

// Round 7
// 518.085 us; speedup vs baseline: 1.6665x; 1.6665x over previous
//
#include <hip/hip_runtime.h>
#include <hip/hip_bf16.h>
#include <math.h>

#define SEQn 2048
#define HID  2048
#define NH   16
#define HD   128

typedef __attribute__((ext_vector_type(8))) __bf16 bf16x8;
typedef __attribute__((ext_vector_type(4))) float  f32x4;

#define MFMA16(a,b,c) __builtin_amdgcn_mfma_f32_16x16x32_bf16((a),(b),(c),0,0,0)

__device__ __forceinline__ ushort f2bf(float f) {
  union { float f; unsigned u; } v; v.f = f;
  unsigned r = v.u + 0x7fffu + ((v.u >> 16) & 1u);
  return (ushort)(r >> 16);
}
__device__ __forceinline__ float bf2f(ushort u) {
  union { unsigned u; float f; } v; v.u = ((unsigned)u) << 16; return v.f;
}
__device__ __forceinline__ void split2(float x, ushort& h, ushort& l) {
  h = f2bf(x);
  l = f2bf(x - bf2f(h));   // x-hi exact; total err <= ~2^-17 |x|
}
__device__ __forceinline__ void gl_lds16(const ushort* g, ushort* l) {
  __builtin_amdgcn_global_load_lds((const __attribute__((address_space(1))) unsigned int*)g,
                                   (__attribute__((address_space(3))) unsigned int*)l, 16, 0, 0);
}

// ---------------- RoPE tables: cos/sin [SEQ][64] ----------------
__global__ void k_rope_tables(const int* __restrict__ pos,
                              float* __restrict__ cosT, float* __restrict__ sinT) {
  int t = threadIdx.x;
  int s = blockIdx.x * 4 + (t >> 6), i = t & 63;
  float p = (float)pos[s];
  float ex = (float)(2 * i) / 128.0f;
  float invf = 1.0f / powf(10000.0f, ex);
  float f = p * invf;
  cosT[s * 64 + i] = cosf(f);
  sinT[s * 64 + i] = sinf(f);
}

// ---------------- split f32 -> bf16 hi/lo (x4 vectorized) ----------------
__global__ void k_split(const float* __restrict__ x,
                        ushort* __restrict__ hi, ushort* __restrict__ lo, int n4) {
  int i = blockIdx.x * blockDim.x + threadIdx.x;
  if (i >= n4) return;
  const float4 v = ((const float4*)x)[i];
  ushort4 h, l;
  split2(v.x, h.x, l.x); split2(v.y, h.y, l.y);
  split2(v.z, h.z, l.z); split2(v.w, h.w, l.w);
  ((ushort4*)hi)[i] = h; ((ushort4*)lo)[i] = l;
}

// ------- transpose + split 3 weights in one dispatch: W[z][K][N] f32 -> WT[z][N][K] bf16 hi/lo ----
__global__ void k_splitT3(const float* __restrict__ W0, const float* __restrict__ W1,
                          const float* __restrict__ W2,
                          ushort* __restrict__ Th, ushort* __restrict__ Tl) {
  __shared__ float tile[32][33];
  const float* W = (blockIdx.z == 0) ? W0 : (blockIdx.z == 1) ? W1 : W2;
  ushort* Thz = Th + (size_t)blockIdx.z * HID * HID;
  ushort* Tlz = Tl + (size_t)blockIdx.z * HID * HID;
  int kb = blockIdx.x * 32, nb = blockIdx.y * 32;
  int tx = threadIdx.x, ty = threadIdx.y;   // 32 x 8
#pragma unroll
  for (int r = 0; r < 4; r++)
    tile[ty + r * 8][tx] = W[(size_t)(kb + ty + r * 8) * HID + nb + tx];
  __syncthreads();
#pragma unroll
  for (int r = 0; r < 4; r++) {
    int n = nb + ty + r * 8, k = kb + tx;
    ushort h, l; split2(tile[tx][ty + r * 8], h, l);
    Thz[(size_t)n * HID + k] = h;
    Tlz[(size_t)n * HID + k] = l;
  }
}

// ---------------- GEMM: C[z][M][N] = A * B[z]^T-stored, bf16x3 (Ah*Bh + Ah*Bl + Al*Bh) ----
__global__ __launch_bounds__(512) void k_gemm_x3(
    const ushort* __restrict__ Ah, const ushort* __restrict__ Al,
    const ushort* __restrict__ Bh, const ushort* __restrict__ Bl,
    float* __restrict__ C) {
  __shared__ alignas(16) ushort lds[4][128 * 32];
  const int t = threadIdx.x, lane = t & 63, w = t >> 6;  // 8 waves
  const int bm = blockIdx.y * 128, bn = blockIdx.x * 128;
  const size_t zb = (size_t)blockIdx.z * HID * HID;
  const int lr = lane & 15, lg = lane >> 4;
  const int sr = t >> 2, sc = (t & 3) * 8;
  const ushort* ga  = Ah + (size_t)(bm + sr) * HID + sc;
  const ushort* gal = Al + (size_t)(bm + sr) * HID + sc;
  const ushort* gb  = Bh + zb + (size_t)(bn + sr) * HID + sc;
  const ushort* gbl = Bl + zb + (size_t)(bn + sr) * HID + sc;
  ushort* l0 = &lds[0][w * 512];   // wave-uniform base; lane*16B == row-major (sr,sc)
  ushort* l1 = &lds[1][w * 512];
  ushort* l2 = &lds[2][w * 512];
  ushort* l3 = &lds[3][w * 512];
  const int wr = (w & 3) * 32, wc = (w >> 2) * 64;   // wave tile: 32 rows x 64 cols
  f32x4 acc[2][4] = {};
  for (int k0 = 0; k0 < HID; k0 += 32) {
    __syncthreads();                      // WAR: all waves done reading previous tile
    gl_lds16(ga  + k0, l0);
    gl_lds16(gal + k0, l1);
    gl_lds16(gb  + k0, l2);
    gl_lds16(gbl + k0, l3);
    __syncthreads();                      // compiler drains vmcnt before s_barrier
    bf16x8 a_h[2], a_l[2], b_h[4], b_l[4];
#pragma unroll
    for (int mi = 0; mi < 2; mi++) {
      int ro = (wr + mi * 16 + lr) * 32 + lg * 8;
      a_h[mi] = *(const bf16x8*)&lds[0][ro];
      a_l[mi] = *(const bf16x8*)&lds[1][ro];
    }
#pragma unroll
    for (int ni = 0; ni < 4; ni++) {
      int ro = (wc + ni * 16 + lr) * 32 + lg * 8;
      b_h[ni] = *(const bf16x8*)&lds[2][ro];
      b_l[ni] = *(const bf16x8*)&lds[3][ro];
    }
#pragma unroll
    for (int mi = 0; mi < 2; mi++)
#pragma unroll
      for (int ni = 0; ni < 4; ni++) {
        acc[mi][ni] = MFMA16(a_h[mi], b_h[ni], acc[mi][ni]);
        acc[mi][ni] = MFMA16(a_h[mi], b_l[ni], acc[mi][ni]);
        acc[mi][ni] = MFMA16(a_l[mi], b_h[ni], acc[mi][ni]);
      }
  }
  float* Cz = C + (size_t)blockIdx.z * SEQn * HID;
#pragma unroll
  for (int mi = 0; mi < 2; mi++)
#pragma unroll
    for (int ni = 0; ni < 4; ni++)
#pragma unroll
      for (int j = 0; j < 4; j++) {
        int row = bm + wr + mi * 16 + lg * 4 + j;   // C/D: row=(lane>>4)*4+j
        int col = bn + wc + ni * 16 + lr;           //      col=lane&15
        Cz[(size_t)row * HID + col] = acc[mi][ni][j];
      }
}

// ---------------- RoPE apply + convert Q,K: [s][h*128+d] f32 -> [h][s][d] bf16 hi/lo ----------------
// Q is pre-scaled by 1/sqrt(HD).
__global__ void k_rope_qk(const float* __restrict__ Qf, const float* __restrict__ Kf,
                          const float* __restrict__ cosT, const float* __restrict__ sinT,
                          ushort* __restrict__ Qhh, ushort* __restrict__ Qll,
                          ushort* __restrict__ Khh, ushort* __restrict__ Kll) {
  int t = threadIdx.x;
  int s = blockIdx.x * 4 + (t >> 6), h = blockIdx.y, d = t & 63;
  const float scale = 0.08838834764831845f;  // 1/sqrt(128)
  float c = cosT[s * 64 + d], sn = sinT[s * 64 + d];
  size_t in0  = (size_t)s * HID + h * HD + d;
  size_t out0 = ((size_t)h * SEQn + s) * HD + d;
  ushort hh, ll;
  {
    float q1 = Qf[in0] * scale, q2 = Qf[in0 + 64] * scale;
    split2(q1 * c - q2 * sn, hh, ll); Qhh[out0] = hh;      Qll[out0] = ll;
    split2(q2 * c + q1 * sn, hh, ll); Qhh[out0 + 64] = hh; Qll[out0 + 64] = ll;
  }
  {
    float k1 = Kf[in0], k2 = Kf[in0 + 64];
    split2(k1 * c - k2 * sn, hh, ll); Khh[out0] = hh;      Kll[out0] = ll;
    split2(k2 * c + k1 * sn, hh, ll); Khh[out0 + 64] = hh; Kll[out0 + 64] = ll;
  }
}

// ---------------- V: [s][h*128+d] f32 -> V^T [h][d][s] bf16 hi/lo ----------------
__global__ void k_transpose_v(const float* __restrict__ Vf,
                              ushort* __restrict__ Vth, ushort* __restrict__ Vtl) {
  __shared__ float tile[32][33];
  int h = blockIdx.x, db = blockIdx.y * 32, sb = blockIdx.z * 32;
  int tx = threadIdx.x, ty = threadIdx.y;  // 32 x 8
#pragma unroll
  for (int r = 0; r < 4; r++)
    tile[ty + r * 8][tx] = Vf[(size_t)(sb + ty + r * 8) * HID + h * HD + db + tx];
  __syncthreads();
#pragma unroll
  for (int r = 0; r < 4; r++) {
    int d = db + ty + r * 8, s = sb + tx;
    ushort hh, ll; split2(tile[tx][ty + r * 8], hh, ll);
    size_t o = ((size_t)h * HD + d) * SEQn + s;
    Vth[o] = hh; Vtl[o] = ll;
  }
}

// ---------------- Flash attention v2: LDS-staged K/V, causal, 4 waves x 16 q-rows ------------
// K/V tiles staged ONCE per block via global_load_lds (was 4x redundant per-wave global reads).
// XOR swizzle byte^=(row&7)<<4 applied on BOTH sides (pre-swizzled global source + swizzled
// ds_read) per rule #21. Balanced block remap: CU slot s gets q-tile qt and 31-qt -> every
// round-robin pair sums to 33 tile-units. P LDS plane reused hi-then-lo (wave-private,
// language-ordered aliasing) to keep LDS at 73KB -> 2 blocks/CU.
__global__ __launch_bounds__(256) void k_attn(
    const ushort* __restrict__ Qhh, const ushort* __restrict__ Qll,
    const ushort* __restrict__ Khh, const ushort* __restrict__ Kll,
    const ushort* __restrict__ Vth, const ushort* __restrict__ Vtl,
    ushort* __restrict__ Ohi, ushort* __restrict__ Olo) {
  __shared__ alignas(16) ushort sKh[64 * 128];   // [kv 64][d 128], swizzled
  __shared__ alignas(16) ushort sKl[64 * 128];
  __shared__ alignas(16) ushort sVh[128 * 64];   // [d 128][kv 64], swizzled
  __shared__ alignas(16) ushort sVl[128 * 64];
  __shared__ alignas(16) ushort sP[4][16 * 72];  // per-wave P tile (hi then lo)
  const int t = threadIdx.x, lane = t & 63, w = t >> 6;
  // balanced (h, q-tile) remap
  const int flat = blockIdx.y * 32 + blockIdx.x;   // 0..511
  const int s_ = flat & 255, halfsel = flat >> 8;
  const int qt_ = s_ & 31, h_ = s_ >> 5;
  const int qt = halfsel ? (31 - qt_) : qt_;
  const int h  = halfsel ? (8 + h_) : h_;
  const int qb = qt * 64;
  const int lr = lane & 15, lg = lane >> 4;
  const int q0 = qb + w * 16;
  const size_t qoff = ((size_t)h * SEQn + q0 + lr) * HD + lg * 8;
  bf16x8 qh[4], ql[4];
#pragma unroll
  for (int ks = 0; ks < 4; ks++) {
    qh[ks] = *(const bf16x8*)(Qhh + qoff + ks * 32);
    ql[ks] = *(const bf16x8*)(Qll + qoff + ks * 32);
  }
  // staging source offsets (inverse-swizzled global addresses; dest is linear lane*16B)
  const int cc = (w << 6) | lane;                 // chunk 0..255 (i adds 256)
  const int rK = cc >> 4;                         // K row 0..15 (+16/i)
  const int cbK = (((cc & 15) << 4) ^ ((rK & 7) << 4)) >> 1;
  const size_t srcKo = (size_t)(h * SEQn + rK) * HD + cbK;
  const int rV = cc >> 3;                         // V row 0..31 (+32/i)
  const int cbV = (((cc & 7) << 4) ^ ((rV & 7) << 4)) >> 1;
  const size_t srcVo = (size_t)(h * HD + rV) * SEQn + cbV;

  f32x4 o[8] = {};
  float mrow[4], lrow[4];
#pragma unroll
  for (int j = 0; j < 4; j++) { mrow[j] = -INFINITY; lrow[j] = 0.f; }
  ushort* myp = &sP[w][0];

  for (int kv0 = 0; kv0 <= qb; kv0 += 64) {
    __syncthreads();                     // WAR: all waves done reading previous K/V tile
    {
      const ushort* gKh = Khh + srcKo + (size_t)kv0 * HD;
      const ushort* gKl = Kll + srcKo + (size_t)kv0 * HD;
      const ushort* gVh = Vth + srcVo + kv0;
      const ushort* gVl = Vtl + srcVo + kv0;
#pragma unroll
      for (int i = 0; i < 4; i++) {
        gl_lds16(gKh + (size_t)i * 16 * HD,  &sKh[(w + i * 4) * 512]);
        gl_lds16(gKl + (size_t)i * 16 * HD,  &sKl[(w + i * 4) * 512]);
        gl_lds16(gVh + (size_t)i * 32 * SEQn, &sVh[(w + i * 4) * 512]);
        gl_lds16(gVl + (size_t)i * 32 * SEQn, &sVl[(w + i * 4) * 512]);
      }
    }
    __syncthreads();                     // drains vmcnt before s_barrier (compiler)
    // ---- scores: S = (Q @ K^T) (pre-scaled), 16 x 64 per wave, bf16x3 from LDS ----
    f32x4 s4[4] = {};
    __builtin_amdgcn_s_setprio(1);
#pragma unroll
    for (int ni = 0; ni < 4; ni++) {
      const int kr = ni * 16 + lr;
      const int kbase = kr * 128;
      const int ksw = (kr & 7) << 4;
#pragma unroll
      for (int ks = 0; ks < 4; ks++) {
        const int off = kbase + (((ks * 64 + lg * 16) ^ ksw) >> 1);
        bf16x8 kh = *(const bf16x8*)&sKh[off];
        bf16x8 kl = *(const bf16x8*)&sKl[off];
        s4[ni] = MFMA16(qh[ks], kh, s4[ni]);
        s4[ni] = MFMA16(qh[ks], kl, s4[ni]);
        s4[ni] = MFMA16(ql[ks], kh, s4[ni]);
      }
    }
    __builtin_amdgcn_s_setprio(0);
    // ---- online softmax (per q-row; rows live in fixed 16-lane groups) ----
    float sf[4];
    ushort pl[4][4];
#pragma unroll
    for (int j = 0; j < 4; j++) {
      const int row = q0 + lg * 4 + j;
      float sc[4];
#pragma unroll
      for (int ni = 0; ni < 4; ni++) {
        int col = kv0 + ni * 16 + lr;
        sc[ni] = (col <= row) ? s4[ni][j] : -INFINITY;
      }
      float rm = fmaxf(fmaxf(sc[0], sc[1]), fmaxf(sc[2], sc[3]));
#pragma unroll
      for (int off = 1; off < 16; off <<= 1) rm = fmaxf(rm, __shfl_xor(rm, off));
      float mn = fmaxf(mrow[j], rm);
      sf[j] = __expf(mrow[j] - mn);
      float rs = 0.f;
#pragma unroll
      for (int ni = 0; ni < 4; ni++) {
        float pv = __expf(sc[ni] - mn);
        rs += pv;
        ushort hh, ll; split2(pv, hh, ll);
        myp[(lg * 4 + j) * 72 + ni * 16 + lr] = hh;   // P-hi into LDS
        pl[j][ni] = ll;                               // P-lo kept in regs
      }
#pragma unroll
      for (int off = 1; off < 16; off <<= 1) rs += __shfl_xor(rs, off);
      lrow[j] = lrow[j] * sf[j] + rs;
      mrow[j] = mn;
    }
#pragma unroll
    for (int nn = 0; nn < 8; nn++) {
      o[nn][0] *= sf[0]; o[nn][1] *= sf[1]; o[nn][2] *= sf[2]; o[nn][3] *= sf[3];
    }
    // ---- P hi frags, then overwrite plane with lo and re-read (wave-private ordering) ----
    bf16x8 p0h = *(const bf16x8*)&myp[lr * 72 + lg * 8];
    bf16x8 p1h = *(const bf16x8*)&myp[lr * 72 + lg * 8 + 32];
#pragma unroll
    for (int j = 0; j < 4; j++)
#pragma unroll
      for (int ni = 0; ni < 4; ni++)
        myp[(lg * 4 + j) * 72 + ni * 16 + lr] = pl[j][ni];
    bf16x8 p0l = *(const bf16x8*)&myp[lr * 72 + lg * 8];
    bf16x8 p1l = *(const bf16x8*)&myp[lr * 72 + lg * 8 + 32];
    // ---- PV from LDS (swizzled V^T), hi/lo x3 ----
    __builtin_amdgcn_s_setprio(1);
#pragma unroll
    for (int nn = 0; nn < 8; nn++) {
      const int d = nn * 16 + lr;
      const int vbase = d * 64;
      const int vsw = (d & 7) << 4;
      const int o0 = vbase + (((lg * 16) ^ vsw) >> 1);
      const int o1 = vbase + (((lg * 16 + 64) ^ vsw) >> 1);
      bf16x8 vh0 = *(const bf16x8*)&sVh[o0];
      bf16x8 vl0 = *(const bf16x8*)&sVl[o0];
      bf16x8 vh1 = *(const bf16x8*)&sVh[o1];
      bf16x8 vl1 = *(const bf16x8*)&sVl[o1];
      o[nn] = MFMA16(p0h, vh0, o[nn]);
      o[nn] = MFMA16(p0h, vl0, o[nn]);
      o[nn] = MFMA16(p0l, vh0, o[nn]);
      o[nn] = MFMA16(p1h, vh1, o[nn]);
      o[nn] = MFMA16(p1h, vl1, o[nn]);
      o[nn] = MFMA16(p1l, vh1, o[nn]);
    }
    __builtin_amdgcn_s_setprio(0);
  }
  // ---- epilogue: normalize + hi/lo split, write [s][h*128+d] ----
#pragma unroll
  for (int nn = 0; nn < 8; nn++)
#pragma unroll
    for (int j = 0; j < 4; j++) {
      int row = q0 + lg * 4 + j;
      int col = h * HD + nn * 16 + lr;
      ushort hh, ll; split2(o[nn][j] / lrow[j], hh, ll);
      Ohi[(size_t)row * HID + col] = hh;
      Olo[(size_t)row * HID + col] = ll;
    }
}

extern "C" void kernel_launch(void* const* d_in, const int* in_sizes, int n_in,
                              void* d_out, int out_size, void* d_ws, size_t ws_size,
                              hipStream_t stream) {
  const float* Hf  = (const float*)d_in[0];
  // d_in[1] = attention_mask (pure causal by construction; applied analytically)
  const int*   pos = (const int*)d_in[2];
  const float* Wq  = (const float*)d_in[3];
  const float* Wk  = (const float*)d_in[4];
  const float* Wv  = (const float*)d_in[5];
  const float* Wo  = (const float*)d_in[6];

  char* ws = (char*)d_ws;
  const size_t SZ_TBL = (size_t)SEQn * 64 * 4;      // 512 KB
  const size_t SZ_BF  = (size_t)SEQn * HID * 2;     // 8 MB  (bf16 plane)
  const size_t SZ_F   = (size_t)SEQn * HID * 4;     // 16 MB (f32 plane)
  const size_t PLANE  = (size_t)HID * HID;          // ushorts per bf16 plane
  size_t off = 0;
  float*  cosT = (float*)(ws + off);  off += SZ_TBL;
  float*  sinT = (float*)(ws + off);  off += SZ_TBL;
  ushort* Hhi  = (ushort*)(ws + off); off += SZ_BF;
  ushort* Hlo  = (ushort*)(ws + off); off += SZ_BF;
  ushort* W3h  = (ushort*)(ws + off); off += 3 * SZ_BF;  // 3 transposed weight planes (hi)
  ushort* W3l  = (ushort*)(ws + off); off += 3 * SZ_BF;  // 3 transposed weight planes (lo)
  float*  QKVf = (float*)(ws + off);  off += 3 * SZ_F;   // Q,K,V f32 contiguous
  // total ws: ~113 MB
  float*  Qf = QKVf;
  float*  Kf = QKVf + (size_t)SEQn * HID;
  float*  Vf = QKVf + 2 * (size_t)SEQn * HID;
  // Overlays (serialized by stream order), as in R5/R6.
  ushort* Qhh = W3h;
  ushort* Qll = W3h + PLANE;
  ushort* Khh = W3h + 2 * PLANE;
  ushort* Kll = W3l;
  ushort* Vth = W3l + PLANE;
  ushort* Vtl = W3l + 2 * PLANE;
  ushort* Ohi = (ushort*)Kf;
  ushort* Olo = (ushort*)((char*)Kf + SZ_BF);

  const int n4 = SEQn * HID / 4;

  k_rope_tables<<<dim3(SEQn / 4), dim3(256), 0, stream>>>(pos, cosT, sinT);
  k_split<<<dim3(n4 / 256), dim3(256), 0, stream>>>(Hf, Hhi, Hlo, n4);

  // all three QKV weights in one dispatch
  k_splitT3<<<dim3(64, 64, 3), dim3(32, 8), 0, stream>>>(Wq, Wk, Wv, W3h, W3l);

  // fused QKV projection: 768 blocks (~3 blocks/CU)
  k_gemm_x3<<<dim3(16, 16, 3), dim3(512), 0, stream>>>(Hhi, Hlo, W3h, W3l, QKVf);

  k_rope_qk<<<dim3(SEQn / 4, NH), dim3(256), 0, stream>>>(Qf, Kf, cosT, sinT, Qhh, Qll, Khh, Kll);
  k_transpose_v<<<dim3(NH, 4, 64), dim3(32, 8), 0, stream>>>(Vf, Vth, Vtl);

  k_attn<<<dim3(SEQn / 64, NH), dim3(256), 0, stream>>>(Qhh, Qll, Khh, Kll, Vth, Vtl, Ohi, Olo);

  // output projection (weight plane 0 reused for Wo; Qhh/Kll dead by now)
  k_splitT3<<<dim3(64, 64, 1), dim3(32, 8), 0, stream>>>(Wo, Wo, Wo, W3h, W3l);
  k_gemm_x3<<<dim3(16, 16, 1), dim3(512), 0, stream>>>(Ohi, Olo, W3h, W3l, (float*)d_out);
}